// Round 1
// baseline (3053.028 us; speedup 1.0000x reference)
//
#include <hip/hip_runtime.h>
#include <hip/hip_bf16.h>
#include <math.h>

constexpr int R_ = 4096;
constexpr int N_ = 128;
constexpr int M_ = R_ * N_;
constexpr int TILE = 32;   // samples per block (within one ray: 32 | 128)
constexpr int NT = 256;    // threads per block

__device__ __forceinline__ float softplusf(float x) {
    // matches jax.nn.softplus = max(x,0) + log1p(exp(-|x|))
    return fmaxf(x, 0.f) + log1pf(expf(-fabsf(x)));
}
__device__ __forceinline__ float sigmoidf(float x) {
    return 1.f / (1.f + expf(-x));
}

__global__ __launch_bounds__(NT) void mlp_kernel(
    const float* __restrict__ ray, const float* __restrict__ t,
    const float* __restrict__ W0, const float* __restrict__ b0,
    const float* __restrict__ W1, const float* __restrict__ b1,
    const float* __restrict__ W2, const float* __restrict__ b2,
    const float* __restrict__ Ws, const float* __restrict__ bs,
    const float* __restrict__ Wc1, const float* __restrict__ bc1,
    const float* __restrict__ Wc2, const float* __restrict__ bc2,
    float* __restrict__ sigma_out, float* __restrict__ color_out)
{
    __shared__ float s_xe[TILE][64];    // 63 used + 1 pad (zeroed)
    __shared__ float s_h[TILE][256];
    __shared__ float s_hc[TILE][128];
    __shared__ float s_de[27];
    __shared__ float s_od[6];

    const int tid = threadIdx.x;
    const int tile0 = blockIdx.x * TILE;
    const int r = tile0 >> 7;    // tile0 / N_
    const int s0 = tile0 & 127;  // tile0 % N_

    if (tid < 6) s_od[tid] = ray[r * 6 + tid];
    __syncthreads();
    const float o0 = s_od[0], o1 = s_od[1], o2 = s_od[2];
    const float d0 = s_od[3], d1 = s_od[4], d2 = s_od[5];

    // de = posenc(d, 4): 27 features, per-ray constant
    if (tid < 27) {
        int f = tid;
        float v;
        if (f < 3) {
            v = (f == 0) ? d0 : ((f == 1) ? d1 : d2);
        } else {
            int q = f - 3, l = q / 6, rm = q % 6, c = rm % 3;
            float dc = (c == 0) ? d0 : ((c == 1) ? d1 : d2);
            float a = dc * (float)(1 << l);
            v = (rm < 3) ? sinf(a) : cosf(a);
        }
        s_de[f] = v;
    }
    // xe = posenc(x, 10): 63 features per point
    for (int i = tid; i < TILE * 63; i += NT) {
        int p = i / 63, f = i % 63;
        float tv = t[r * (N_ + 1) + 1 + s0 + p];
        float x0 = o0 + tv * d0, x1 = o1 + tv * d1, x2 = o2 + tv * d2;
        float v;
        if (f < 3) {
            v = (f == 0) ? x0 : ((f == 1) ? x1 : x2);
        } else {
            int q = f - 3, l = q / 6, rm = q % 6, c = rm % 3;
            float xc = (c == 0) ? x0 : ((c == 1) ? x1 : x2);
            float a = xc * (float)(1 << l);
            v = (rm < 3) ? sinf(a) : cosf(a);
        }
        s_xe[p][f] = v;
    }
    if (tid < TILE) s_xe[tid][63] = 0.f;
    __syncthreads();

    // ---- layer 0: [32 x 63] @ [63 x 256], thread = output column j ----
    {
        const int j = tid;
        float acc[TILE];
        const float bj = b0[j];
        #pragma unroll
        for (int p = 0; p < TILE; ++p) acc[p] = bj;
        for (int k4 = 0; k4 < 60; k4 += 4) {
            float w0 = W0[(k4 + 0) * 256 + j];
            float w1 = W0[(k4 + 1) * 256 + j];
            float w2 = W0[(k4 + 2) * 256 + j];
            float w3 = W0[(k4 + 3) * 256 + j];
            #pragma unroll
            for (int p = 0; p < TILE; ++p) {
                float4 hv = *reinterpret_cast<const float4*>(&s_xe[p][k4]);
                acc[p] = fmaf(hv.x, w0, acc[p]);
                acc[p] = fmaf(hv.y, w1, acc[p]);
                acc[p] = fmaf(hv.z, w2, acc[p]);
                acc[p] = fmaf(hv.w, w3, acc[p]);
            }
        }
        for (int k = 60; k < 63; ++k) {
            float w = W0[k * 256 + j];
            #pragma unroll
            for (int p = 0; p < TILE; ++p)
                acc[p] = fmaf(s_xe[p][k], w, acc[p]);
        }
        #pragma unroll
        for (int p = 0; p < TILE; ++p) s_h[p][j] = fmaxf(acc[p], 0.f);
    }
    __syncthreads();

    // ---- layers 1,2: [32 x 256] @ [256 x 256]; thread = (point-half, 2 cols) ----
    for (int layer = 0; layer < 2; ++layer) {
        const float* __restrict__ W = layer ? W2 : W1;
        const float* __restrict__ b = layer ? b2 : b1;
        const int j = tid & 127;
        const int pb = (tid >> 7) * 16;
        float acc0[16], acc1[16];
        const float bj0 = b[j], bj1 = b[j + 128];
        #pragma unroll
        for (int p = 0; p < 16; ++p) { acc0[p] = bj0; acc1[p] = bj1; }
        for (int k4 = 0; k4 < 256; k4 += 4) {
            float wa0 = W[(k4 + 0) * 256 + j];
            float wa1 = W[(k4 + 1) * 256 + j];
            float wa2 = W[(k4 + 2) * 256 + j];
            float wa3 = W[(k4 + 3) * 256 + j];
            float wb0 = W[(k4 + 0) * 256 + j + 128];
            float wb1 = W[(k4 + 1) * 256 + j + 128];
            float wb2 = W[(k4 + 2) * 256 + j + 128];
            float wb3 = W[(k4 + 3) * 256 + j + 128];
            #pragma unroll
            for (int p = 0; p < 16; ++p) {
                float4 hv = *reinterpret_cast<const float4*>(&s_h[pb + p][k4]);
                acc0[p] = fmaf(hv.x, wa0, acc0[p]);
                acc0[p] = fmaf(hv.y, wa1, acc0[p]);
                acc0[p] = fmaf(hv.z, wa2, acc0[p]);
                acc0[p] = fmaf(hv.w, wa3, acc0[p]);
                acc1[p] = fmaf(hv.x, wb0, acc1[p]);
                acc1[p] = fmaf(hv.y, wb1, acc1[p]);
                acc1[p] = fmaf(hv.z, wb2, acc1[p]);
                acc1[p] = fmaf(hv.w, wb3, acc1[p]);
            }
        }
        __syncthreads();   // all reads of s_h done before overwrite
        #pragma unroll
        for (int p = 0; p < 16; ++p) {
            s_h[pb + p][j]       = fmaxf(acc0[p], 0.f);
            s_h[pb + p][j + 128] = fmaxf(acc1[p], 0.f);
        }
        __syncthreads();
    }

    // ---- sigma = softplus(h @ Ws + bs): 8 threads per point ----
    {
        const int p = tid >> 3;   // 0..31
        const int g = tid & 7;    // 0..7
        const int k0 = g * 32;
        float partial = 0.f;
        #pragma unroll
        for (int kk = 0; kk < 32; kk += 4) {
            float4 hv = *reinterpret_cast<const float4*>(&s_h[p][k0 + kk]);
            float4 wv = *reinterpret_cast<const float4*>(&Ws[k0 + kk]);
            partial += hv.x * wv.x + hv.y * wv.y + hv.z * wv.z + hv.w * wv.w;
        }
        partial += __shfl_xor(partial, 1);
        partial += __shfl_xor(partial, 2);
        partial += __shfl_xor(partial, 4);
        if (g == 0) sigma_out[tile0 + p] = softplusf(partial + bs[0]);
    }

    // ---- hc = relu(concat(h, de) @ Wc1 + bc1): 128 cols ----
    {
        const int j = tid & 127;
        const int pb = (tid >> 7) * 16;
        float acc[16];
        const float bj = bc1[j];
        #pragma unroll
        for (int p = 0; p < 16; ++p) acc[p] = bj;
        for (int k4 = 0; k4 < 256; k4 += 4) {
            float w0 = Wc1[(k4 + 0) * 128 + j];
            float w1 = Wc1[(k4 + 1) * 128 + j];
            float w2 = Wc1[(k4 + 2) * 128 + j];
            float w3 = Wc1[(k4 + 3) * 128 + j];
            #pragma unroll
            for (int p = 0; p < 16; ++p) {
                float4 hv = *reinterpret_cast<const float4*>(&s_h[pb + p][k4]);
                acc[p] = fmaf(hv.x, w0, acc[p]);
                acc[p] = fmaf(hv.y, w1, acc[p]);
                acc[p] = fmaf(hv.z, w2, acc[p]);
                acc[p] = fmaf(hv.w, w3, acc[p]);
            }
        }
        // de part is identical for every point in the tile (same ray)
        float desum = 0.f;
        for (int k = 0; k < 27; ++k)
            desum = fmaf(s_de[k], Wc1[(256 + k) * 128 + j], desum);
        #pragma unroll
        for (int p = 0; p < 16; ++p)
            s_hc[pb + p][j] = fmaxf(acc[p] + desum, 0.f);
    }
    __syncthreads();

    // ---- color = sigmoid(hc @ Wc2 + bc2): 32 points x 3 channels ----
    if (tid < 96) {
        const int p = tid / 3, c = tid % 3;
        float acc = bc2[c];
        for (int k = 0; k < 128; ++k)
            acc = fmaf(s_hc[p][k], Wc2[k * 3 + c], acc);
        color_out[(tile0 + p) * 3 + c] = sigmoidf(acc);
    }
}

__global__ __launch_bounds__(192) void render_kernel(
    const float* __restrict__ t,
    const float* __restrict__ sigma,
    const float* __restrict__ color,
    float* __restrict__ rgb_out,
    float* __restrict__ wi_out)
{
    const int r = blockIdx.x;
    const int tid = threadIdx.x;
    __shared__ float s_t[129];
    __shared__ float s_ts[129];
    __shared__ float s_sdt[128];
    __shared__ float s_cum[128];
    __shared__ float s_wi[128];

    if (tid < 129) s_t[tid] = t[r * 129 + tid];
    __syncthreads();
    // rank sort (stable, tie-broken by index): 129 values
    if (tid < 129) {
        float v = s_t[tid];
        int rank = 0;
        for (int j = 0; j < 129; ++j) {
            float u = s_t[j];
            rank += (u < v) || (u == v && j < tid);
        }
        s_ts[rank] = v;
    }
    __syncthreads();
    if (tid < 128) {
        float dt = s_ts[tid + 1] - s_ts[tid];
        float sd = sigma[r * 128 + tid] * dt;
        s_sdt[tid] = sd;
        s_cum[tid] = sd;
    }
    __syncthreads();
    // inclusive scan (Hillis-Steele)
    for (int off = 1; off < 128; off <<= 1) {
        float add = 0.f;
        if (tid < 128 && tid >= off) add = s_cum[tid - off];
        __syncthreads();
        if (tid < 128) s_cum[tid] += add;
        __syncthreads();
    }
    if (tid < 128) {
        float sd = s_sdt[tid];
        float Ti = (tid == 0) ? 1.f : expf(-s_cum[tid - 1]);
        float alpha = 1.f - expf(-sd);
        float w = Ti * alpha;
        s_wi[tid] = w;
        wi_out[r * 128 + tid] = w;
    }
    __syncthreads();
    if (tid < 3) {
        float acc = 0.f;
        for (int i = 0; i < 128; ++i)
            acc = fmaf(s_wi[i], color[(r * 128 + i) * 3 + tid], acc);
        rgb_out[r * 3 + tid] = acc;
    }
}

extern "C" void kernel_launch(void* const* d_in, const int* in_sizes, int n_in,
                              void* d_out, int out_size, void* d_ws, size_t ws_size,
                              hipStream_t stream)
{
    const float* ray = (const float*)d_in[0];
    const float* t   = (const float*)d_in[1];
    const float* W0  = (const float*)d_in[2];
    const float* b0  = (const float*)d_in[3];
    const float* W1  = (const float*)d_in[4];
    const float* b1  = (const float*)d_in[5];
    const float* W2  = (const float*)d_in[6];
    const float* b2  = (const float*)d_in[7];
    const float* Ws  = (const float*)d_in[8];
    const float* bs  = (const float*)d_in[9];
    const float* Wc1 = (const float*)d_in[10];
    const float* bc1 = (const float*)d_in[11];
    const float* Wc2 = (const float*)d_in[12];
    const float* bc2 = (const float*)d_in[13];

    float* sigma  = (float*)d_ws;          // M_ floats (2 MB)
    float* colorb = sigma + M_;            // M_*3 floats (6 MB)
    float* rgb_out = (float*)d_out;        // R_*3
    float* wi_out  = rgb_out + R_ * 3;     // R_*N_

    hipLaunchKernelGGL(mlp_kernel, dim3(M_ / TILE), dim3(NT), 0, stream,
        ray, t, W0, b0, W1, b1, W2, b2, Ws, bs, Wc1, bc1, Wc2, bc2,
        sigma, colorb);
    hipLaunchKernelGGL(render_kernel, dim3(R_), dim3(192), 0, stream,
        t, sigma, colorb, rgb_out, wi_out);
}

// Round 2
// 556.378 us; speedup vs baseline: 5.4873x; 5.4873x over previous
//
#include <hip/hip_runtime.h>
#include <hip/hip_bf16.h>
#include <math.h>

constexpr int R_ = 4096;
constexpr int N_ = 128;

typedef __attribute__((ext_vector_type(8))) short short8;
typedef __attribute__((ext_vector_type(4))) float f32x4;
typedef __attribute__((ext_vector_type(4))) unsigned int uint4v;

#define MFMA16(a, b, c) __builtin_amdgcn_mfma_f32_16x16x32_bf16(a, b, c, 0, 0, 0)

__device__ __forceinline__ unsigned short f2bf(float f) {
    unsigned int u = __float_as_uint(f);
    u += 0x7fffu + ((u >> 16) & 1u);   // RNE
    return (unsigned short)(u >> 16);
}
__device__ __forceinline__ float bf2f(unsigned short h) {
    return __uint_as_float(((unsigned int)h) << 16);
}

// ---------------------------------------------------------------------------
// Weight prep: build bf16, transposed ([N][K]) and XOR-swizzled weight images.
// elem offset within a region: n*Kpad + (k ^ ((n&7)<<3))   (bytes: ^ (n&7)<<4)
// Regions (elems): Wt0 [0,16384) K=64(real 63), Wt1 [16384,81920) K=256,
//                  Wt2 [81920,147456) K=256,   Wtc1 [147456,180224) K=256 N=128
// ---------------------------------------------------------------------------
__global__ __launch_bounds__(256) void prep_weights(
    const float* __restrict__ W0, const float* __restrict__ W1,
    const float* __restrict__ W2, const float* __restrict__ Wc1,
    unsigned short* __restrict__ out)
{
    int i = blockIdx.x * 256 + threadIdx.x;
    if (i >= 180224) return;
    float val; int dst;
    if (i < 16384) {
        int n = i >> 6, k = i & 63;
        val = (k < 63) ? W0[k * 256 + n] : 0.f;
        dst = 0 + n * 64 + (k ^ ((n & 7) << 3));
    } else if (i < 81920) {
        int e = i - 16384, n = e >> 8, k = e & 255;
        val = W1[k * 256 + n];
        dst = 16384 + n * 256 + (k ^ ((n & 7) << 3));
    } else if (i < 147456) {
        int e = i - 81920, n = e >> 8, k = e & 255;
        val = W2[k * 256 + n];
        dst = 81920 + n * 256 + (k ^ ((n & 7) << 3));
    } else {
        int e = i - 147456, n = e >> 8, k = e & 255;   // n in [0,128)
        val = Wc1[k * 128 + n];
        dst = 147456 + n * 256 + (k ^ ((n & 7) << 3));
    }
    out[dst] = f2bf(val);
}

// ---------------------------------------------------------------------------
// Fused NeRF kernel: 1 block = 1 ray (128 samples), 512 threads = 8 waves.
// ---------------------------------------------------------------------------
__global__ __launch_bounds__(512) void nerf_kernel(
    const float* __restrict__ ray, const float* __restrict__ t,
    const float* __restrict__ b0g, const float* __restrict__ b1g,
    const float* __restrict__ b2g,
    const float* __restrict__ Wsg, const float* __restrict__ bsg,
    const float* __restrict__ Wc1g, const float* __restrict__ bc1g,
    const float* __restrict__ Wc2g, const float* __restrict__ bc2g,
    const unsigned char* __restrict__ wt,
    float* __restrict__ rgb_out, float* __restrict__ wi_out)
{
    __shared__ __align__(16) unsigned char s_act[128 * 512];   // 64 KB bf16 acts
    __shared__ __align__(16) unsigned char s_w[2 * 32768];     // 64 KB weight dbuf
    __shared__ float s_bias[256];
    __shared__ float s_ws[256];
    __shared__ float s_wc2[384];
    __shared__ float s_decont[128];
    __shared__ float s_sigma[128];
    __shared__ float s_color[384];
    __shared__ float s_de[27];
    __shared__ float s_od[6];
    __shared__ float s_t[129];
    __shared__ float s_ts[129];
    __shared__ float s_sdt[128];
    __shared__ float s_cum[128];
    __shared__ float s_wi[128];

    const int tid  = threadIdx.x;
    const int wave = tid >> 6;
    const int lane = tid & 63;
    const int r    = blockIdx.x;

    const int lcol = lane & 15;      // A-row / B-row / C-col lane index
    const int kq   = lane >> 4;      // k-quarter
    const int arow = wave * 16 + lcol;
    const int aswz = (arow & 7) << 4;
    const int bswz = (lane & 7) << 4;

    if (tid < 6) s_od[tid] = ray[r * 6 + tid];
    __syncthreads();
    const float o0 = s_od[0], o1 = s_od[1], o2 = s_od[2];
    const float d0 = s_od[3], d1 = s_od[4], d2 = s_od[5];

    // de = posenc(d, 4)
    if (tid < 27) {
        int f = tid; float v;
        if (f < 3) v = (f == 0) ? d0 : ((f == 1) ? d1 : d2);
        else {
            int q = f - 3, l = q / 6, rm = q % 6, c = rm % 3;
            float dc = (c == 0) ? d0 : ((c == 1) ? d1 : d2);
            float a = dc * (float)(1 << l);
            v = (rm < 3) ? sinf(a) : cosf(a);
        }
        s_de[f] = v;
    }
    if (tid < 256) s_ws[tid]  = Wsg[tid];
    if (tid < 384) s_wc2[tid] = Wc2g[tid];

    // xe = posenc(x, 10) -> s_act cols 0..62 (bf16, swizzled), col 63 zero
    for (int i = tid; i < 128 * 63; i += 512) {
        int p = i / 63, f = i - p * 63;
        float tv = t[r * 129 + 1 + p];
        float x0 = o0 + tv * d0, x1 = o1 + tv * d1, x2 = o2 + tv * d2;
        float v;
        if (f < 3) v = (f == 0) ? x0 : ((f == 1) ? x1 : x2);
        else {
            int q = f - 3, l = q / 6, rm = q % 6, c = rm % 3;
            float xc = (c == 0) ? x0 : ((c == 1) ? x1 : x2);
            float a = xc * (float)(1 << l);
            v = (rm < 3) ? sinf(a) : cosf(a);
        }
        *(unsigned short*)(s_act + p * 512 + ((2 * f) ^ ((p & 7) << 4))) = f2bf(v);
    }
    if (tid < 128)
        *(unsigned short*)(s_act + tid * 512 + (126 ^ ((tid & 7) << 4))) = 0;
    __syncthreads();

    // decont[j] = bc1[j] + sum_k de[k] * Wc1[256+k][j]
    if (tid < 128) {
        float acc = bc1g[tid];
        for (int k = 0; k < 27; ++k)
            acc = fmaf(s_de[k], Wc1g[(256 + k) * 128 + tid], acc);
        s_decont[tid] = acc;
    }

    // ================= Layer 0: [128x64(63)] @ Wt0 -> 256 cols ==============
    {
        const uint4v* g0 = (const uint4v*)wt;          // Wt0 image, 32 KB
        uint4v st0 = g0[tid], st1 = g0[tid + 512], st2 = g0[tid + 1024], st3 = g0[tid + 1536];
        float bv = (tid < 256) ? b0g[tid] : 0.f;
        short8 a0 = *(const short8*)(s_act + arow * 512 + ((kq * 16) ^ aswz));
        short8 a1 = *(const short8*)(s_act + arow * 512 + ((64 + kq * 16) ^ aswz));
        uint4v* dsw = (uint4v*)s_w;
        dsw[tid] = st0; dsw[tid + 512] = st1; dsw[tid + 1024] = st2; dsw[tid + 1536] = st3;
        if (tid < 256) s_bias[tid] = bv;
        __syncthreads();
        #pragma unroll
        for (int half = 0; half < 8; ++half) {
            const int nt0 = half * 2, nt1 = half * 2 + 1;
            f32x4 acc0 = {0.f,0.f,0.f,0.f}, acc1 = {0.f,0.f,0.f,0.f};
            const unsigned char* b0p = s_w + (nt0 * 16 + lcol) * 128;
            const unsigned char* b1p = s_w + (nt1 * 16 + lcol) * 128;
            #pragma unroll
            for (int ks = 0; ks < 2; ++ks) {
                int boff = (ks * 64 + kq * 16) ^ bswz;
                short8 bb0 = *(const short8*)(b0p + boff);
                short8 bb1 = *(const short8*)(b1p + boff);
                acc0 = MFMA16(ks ? a1 : a0, bb0, acc0);
                acc1 = MFMA16(ks ? a1 : a0, bb1, acc1);
            }
            #pragma unroll
            for (int pair = 0; pair < 2; ++pair) {
                f32x4 acc = pair ? acc1 : acc0;
                int nt = pair ? nt1 : nt0;
                int col = nt * 16 + lcol;
                float bias = s_bias[col];
                #pragma unroll
                for (int i = 0; i < 4; ++i) {
                    int row = wave * 16 + kq * 4 + i;
                    float v = fmaxf(acc[i] + bias, 0.f);
                    *(unsigned short*)(s_act + row * 512 + ((2 * col) ^ ((row & 7) << 4))) = f2bf(v);
                }
            }
        }
        __syncthreads();
    }

    // ============ Layers 1,2 (256->256) and Wc1 (256->128), K=256 ==========
    #pragma unroll 1
    for (int L = 0; L < 3; ++L) {
        const unsigned char* img =
            (L == 0) ? (wt + 32768) : (L == 1) ? (wt + 163840) : (wt + 294912);
        const float* gbias = (L == 0) ? b1g : (L == 1) ? b2g : nullptr;
        const float* biasvec = (L == 2) ? s_decont : s_bias;
        const int nchunks = (L == 2) ? 2 : 4;

        // sigma head goes between L2 and Wc1 (needs h3 before overwrite)
        if (L == 2) {
            const int p = tid >> 2, q = tid & 3;
            const int pswz = (p & 7) << 4;
            float sum = 0.f;
            #pragma unroll
            for (int g = 0; g < 8; ++g) {
                short8 h = *(const short8*)(s_act + p * 512 + ((q * 128 + g * 16) ^ pswz));
                int kb = q * 64 + g * 8;
                #pragma unroll
                for (int j = 0; j < 8; ++j)
                    sum = fmaf(bf2f((unsigned short)h[j]), s_ws[kb + j], sum);
            }
            sum += __shfl_xor(sum, 1);
            sum += __shfl_xor(sum, 2);
            if (q == 0) {
                float x = sum + bsg[0];
                s_sigma[p] = fmaxf(x, 0.f) + log1pf(expf(-fabsf(x)));
            }
            __syncthreads();
        }

        // prologue: chunk-0 loads + A-frags + bias
        const uint4v* g0 = (const uint4v*)img;
        uint4v st0 = g0[tid], st1 = g0[tid + 512], st2 = g0[tid + 1024], st3 = g0[tid + 1536];
        float bv = 0.f;
        if (gbias && tid < 256) bv = gbias[tid];
        short8 a[8];
        #pragma unroll
        for (int ks = 0; ks < 8; ++ks)
            a[ks] = *(const short8*)(s_act + arow * 512 + ((ks * 64 + kq * 16) ^ aswz));
        uint4v* dsw = (uint4v*)s_w;
        dsw[tid] = st0; dsw[tid + 512] = st1; dsw[tid + 1024] = st2; dsw[tid + 1536] = st3;
        if (gbias && tid < 256) s_bias[tid] = bv;
        __syncthreads();

        for (int c = 0; c < nchunks; ++c) {
            uint4v n0, n1, n2, n3;
            const bool more = (c + 1 < nchunks);
            if (more) {
                const uint4v* gn = (const uint4v*)(img + (size_t)(c + 1) * 32768);
                n0 = gn[tid]; n1 = gn[tid + 512]; n2 = gn[tid + 1024]; n3 = gn[tid + 1536];
            }
            const unsigned char* wbuf = s_w + (c & 1) * 32768;
            #pragma unroll
            for (int half = 0; half < 2; ++half) {
                const int ntl0 = half * 2, ntl1 = half * 2 + 1;
                f32x4 acc0 = {0.f,0.f,0.f,0.f}, acc1 = {0.f,0.f,0.f,0.f};
                const unsigned char* b0p = wbuf + (ntl0 * 16 + lcol) * 512;
                const unsigned char* b1p = wbuf + (ntl1 * 16 + lcol) * 512;
                #pragma unroll
                for (int ks = 0; ks < 8; ++ks) {
                    int boff = (ks * 64 + kq * 16) ^ bswz;
                    short8 bb0 = *(const short8*)(b0p + boff);
                    short8 bb1 = *(const short8*)(b1p + boff);
                    acc0 = MFMA16(a[ks], bb0, acc0);
                    acc1 = MFMA16(a[ks], bb1, acc1);
                }
                #pragma unroll
                for (int pair = 0; pair < 2; ++pair) {
                    f32x4 acc = pair ? acc1 : acc0;
                    int nt = c * 4 + (pair ? ntl1 : ntl0);
                    int col = nt * 16 + lcol;
                    float bias = biasvec[col];
                    #pragma unroll
                    for (int i = 0; i < 4; ++i) {
                        int row = wave * 16 + kq * 4 + i;
                        float v = fmaxf(acc[i] + bias, 0.f);
                        *(unsigned short*)(s_act + row * 512 + ((2 * col) ^ ((row & 7) << 4))) = f2bf(v);
                    }
                }
            }
            if (more) {
                uint4v* dsn = (uint4v*)(s_w + ((c + 1) & 1) * 32768);
                dsn[tid] = n0; dsn[tid + 512] = n1; dsn[tid + 1024] = n2; dsn[tid + 1536] = n3;
            }
            __syncthreads();
        }
    }

    // ================= color head: sigmoid(hc @ Wc2 + bc2) ==================
    {
        const int p = tid >> 2, q = tid & 3;
        const int pswz = (p & 7) << 4;
        float c0 = 0.f, c1 = 0.f, c2 = 0.f;
        #pragma unroll
        for (int g = 0; g < 4; ++g) {
            short8 h = *(const short8*)(s_act + p * 512 + ((q * 64 + g * 16) ^ pswz));
            int kb = q * 32 + g * 8;
            #pragma unroll
            for (int j = 0; j < 8; ++j) {
                float hv = bf2f((unsigned short)h[j]);
                c0 = fmaf(hv, s_wc2[(kb + j) * 3 + 0], c0);
                c1 = fmaf(hv, s_wc2[(kb + j) * 3 + 1], c1);
                c2 = fmaf(hv, s_wc2[(kb + j) * 3 + 2], c2);
            }
        }
        c0 += __shfl_xor(c0, 1); c0 += __shfl_xor(c0, 2);
        c1 += __shfl_xor(c1, 1); c1 += __shfl_xor(c1, 2);
        c2 += __shfl_xor(c2, 1); c2 += __shfl_xor(c2, 2);
        if (q == 0) {
            s_color[p * 3 + 0] = 1.f / (1.f + expf(-(c0 + bc2g[0])));
            s_color[p * 3 + 1] = 1.f / (1.f + expf(-(c1 + bc2g[1])));
            s_color[p * 3 + 2] = 1.f / (1.f + expf(-(c2 + bc2g[2])));
        }
    }
    __syncthreads();

    // ======================= render (sort/scan/composite) ===================
    if (tid < 129) s_t[tid] = t[r * 129 + tid];
    __syncthreads();
    if (tid < 129) {
        float v = s_t[tid];
        int rank = 0;
        for (int j = 0; j < 129; ++j) {
            float u = s_t[j];
            rank += (u < v) || (u == v && j < tid);
        }
        s_ts[rank] = v;
    }
    __syncthreads();
    if (tid < 128) {
        float dt = s_ts[tid + 1] - s_ts[tid];
        float sd = s_sigma[tid] * dt;
        s_sdt[tid] = sd;
        s_cum[tid] = sd;
    }
    __syncthreads();
    for (int off = 1; off < 128; off <<= 1) {
        float add = (tid < 128 && tid >= off) ? s_cum[tid - off] : 0.f;
        __syncthreads();
        if (tid < 128) s_cum[tid] += add;
        __syncthreads();
    }
    if (tid < 128) {
        float Ti = (tid == 0) ? 1.f : expf(-s_cum[tid - 1]);
        float alpha = 1.f - expf(-s_sdt[tid]);
        float w = Ti * alpha;
        s_wi[tid] = w;
        wi_out[r * 128 + tid] = w;
    }
    __syncthreads();
    if (tid < 3) {
        float acc = 0.f;
        for (int i = 0; i < 128; ++i)
            acc = fmaf(s_wi[i], s_color[i * 3 + tid], acc);
        rgb_out[r * 3 + tid] = acc;
    }
}

extern "C" void kernel_launch(void* const* d_in, const int* in_sizes, int n_in,
                              void* d_out, int out_size, void* d_ws, size_t ws_size,
                              hipStream_t stream)
{
    const float* ray = (const float*)d_in[0];
    const float* t   = (const float*)d_in[1];
    const float* W0  = (const float*)d_in[2];
    const float* b0  = (const float*)d_in[3];
    const float* W1  = (const float*)d_in[4];
    const float* b1  = (const float*)d_in[5];
    const float* W2  = (const float*)d_in[6];
    const float* b2  = (const float*)d_in[7];
    const float* Ws  = (const float*)d_in[8];
    const float* bs  = (const float*)d_in[9];
    const float* Wc1 = (const float*)d_in[10];
    const float* bc1 = (const float*)d_in[11];
    const float* Wc2 = (const float*)d_in[12];
    const float* bc2 = (const float*)d_in[13];

    unsigned short* wt = (unsigned short*)d_ws;   // 360448 bytes of weight images
    float* rgb_out = (float*)d_out;               // R*3
    float* wi_out  = rgb_out + R_ * 3;            // R*128

    hipLaunchKernelGGL(prep_weights, dim3(704), dim3(256), 0, stream,
                       W0, W1, W2, Wc1, wt);
    hipLaunchKernelGGL(nerf_kernel, dim3(R_), dim3(512), 0, stream,
                       ray, t, b0, b1, b2, Ws, bs, Wc1, bc1, Wc2, bc2,
                       (const unsigned char*)wt, rgb_out, wi_out);
}

// Round 3
// 399.330 us; speedup vs baseline: 7.6454x; 1.3933x over previous
//
#include <hip/hip_runtime.h>
#include <hip/hip_bf16.h>
#include <math.h>

constexpr int R_ = 4096;
constexpr int N_ = 128;

typedef __attribute__((ext_vector_type(8))) short short8;
typedef __attribute__((ext_vector_type(4))) float f32x4;
typedef __attribute__((ext_vector_type(16))) float f32x16;
typedef __attribute__((ext_vector_type(4))) unsigned int uint4v;

#define MFMA32(a, b, c) __builtin_amdgcn_mfma_f32_32x32x16_bf16(a, b, c, 0, 0, 0)

__device__ __forceinline__ unsigned short f2bf(float f) {
    unsigned int u = __float_as_uint(f);
    u += 0x7fffu + ((u >> 16) & 1u);   // RNE
    return (unsigned short)(u >> 16);
}
__device__ __forceinline__ float bf2f(unsigned short h) {
    return __uint_as_float(((unsigned int)h) << 16);
}

// ---------------------------------------------------------------------------
// Weight prep: bf16, transposed ([N][Kpad]), XOR-swizzled images, CONTIGUOUS:
//   elem dst within region: n*Kpad + (k ^ ((n&7)<<3))   (bytes: ^ ((n&7)<<4))
//   chunk c (32KB) lives at wt + c*32768, c = 0..10:
//   c0: W0t (256n x 64k), c1-4: W1t (256x256), c5-8: W2t, c9-10: Wc1t (128x256)
// ---------------------------------------------------------------------------
__global__ __launch_bounds__(256) void prep_weights(
    const float* __restrict__ W0, const float* __restrict__ W1,
    const float* __restrict__ W2, const float* __restrict__ Wc1,
    unsigned short* __restrict__ out)
{
    int i = blockIdx.x * 256 + threadIdx.x;
    if (i >= 180224) return;
    float val; int dst;
    if (i < 16384) {
        int n = i >> 6, k = i & 63;
        val = (k < 63) ? W0[k * 256 + n] : 0.f;
        dst = 0 + n * 64 + (k ^ ((n & 7) << 3));
    } else if (i < 81920) {
        int e = i - 16384, n = e >> 8, k = e & 255;
        val = W1[k * 256 + n];
        dst = 16384 + n * 256 + (k ^ ((n & 7) << 3));
    } else if (i < 147456) {
        int e = i - 81920, n = e >> 8, k = e & 255;
        val = W2[k * 256 + n];
        dst = 81920 + n * 256 + (k ^ ((n & 7) << 3));
    } else {
        int e = i - 147456, n = e >> 8, k = e & 255;   // n in [0,128)
        val = Wc1[k * 128 + n];
        dst = 147456 + n * 256 + (k ^ ((n & 7) << 3));
    }
    out[dst] = f2bf(val);
}

// One K=256 chunk: acc init from bias, 16 MFMAs, relu+pack+b64 epilogue.
__device__ __forceinline__ void mfma_chunk_k256(
    const unsigned char* __restrict__ ap,   // s_w buf + (cgrp*32+ls)*512
    const short8 (&Bf)[16],
    const float* __restrict__ biasvec, int nb,
    int hi, int swz, unsigned char* __restrict__ wp)
{
    f32x16 acc;
    #pragma unroll
    for (int g = 0; g < 4; ++g) {
        f32x4 bv = *(const f32x4*)&biasvec[nb + 4 * hi + 8 * g];
        acc[4*g+0] = bv[0]; acc[4*g+1] = bv[1]; acc[4*g+2] = bv[2]; acc[4*g+3] = bv[3];
    }
    #pragma unroll
    for (int ks = 0; ks < 16; ++ks) {
        short8 A = *(const short8*)(ap + ((32 * ks + 16 * hi) ^ swz));
        acc = MFMA32(A, Bf[ks], acc);
    }
    #pragma unroll
    for (int g = 0; g < 4; ++g) {
        int n = nb + 4 * hi + 8 * g;
        unsigned long long pk =
              (unsigned long long)f2bf(fmaxf(acc[4*g+0], 0.f))
            | ((unsigned long long)f2bf(fmaxf(acc[4*g+1], 0.f)) << 16)
            | ((unsigned long long)f2bf(fmaxf(acc[4*g+2], 0.f)) << 32)
            | ((unsigned long long)f2bf(fmaxf(acc[4*g+3], 0.f)) << 48);
        *(unsigned long long*)(wp + ((2 * n) ^ swz)) = pk;
    }
}

// ---------------------------------------------------------------------------
// Fused NeRF kernel: 1 block = 1 ray (128 samples), 512 threads = 8 waves.
// Wave roles: st = wave&3 (32-sample tile), cgrp = wave>>2 (col half of chunk).
// ---------------------------------------------------------------------------
__global__ __launch_bounds__(512, 2) void nerf_kernel(
    const float* __restrict__ ray, const float* __restrict__ t,
    const float* __restrict__ b0g, const float* __restrict__ b1g,
    const float* __restrict__ b2g,
    const float* __restrict__ Wsg, const float* __restrict__ bsg,
    const float* __restrict__ Wc1g, const float* __restrict__ bc1g,
    const float* __restrict__ Wc2g, const float* __restrict__ bc2g,
    const unsigned char* __restrict__ wt,
    float* __restrict__ rgb_out, float* __restrict__ wi_out)
{
    __shared__ __align__(16) unsigned char s_act[128 * 512];   // 64 KB bf16 acts
    __shared__ __align__(16) unsigned char s_w[2 * 32768];     // 64 KB weight dbuf
    __shared__ __align__(16) float s_bias[256];
    __shared__ __align__(16) float s_decont[128];
    __shared__ float s_ws[256];
    __shared__ float s_wc2[384];
    __shared__ float s_sigma[128];
    __shared__ float s_color[384];
    __shared__ float s_de[27];
    __shared__ float s_od[6];
    __shared__ float s_t[129];
    __shared__ float s_ts[129];
    __shared__ float s_sdt[128];
    __shared__ float s_cum[128];
    __shared__ float s_wi[128];

    const int tid  = threadIdx.x;
    const int wave = tid >> 6;
    const int lane = tid & 63;
    const int r    = blockIdx.x;

    const int st   = wave & 3;       // sample tile (32 rows)
    const int cgrp = wave >> 2;      // which 32-col half of a 64-col chunk
    const int ls   = lane & 31;
    const int hi   = lane >> 5;
    const int row  = st * 32 + ls;   // this lane's activation row (B operand)
    const int swz  = (ls & 7) << 4;
    unsigned char* const wp = s_act + row * 512;

    uint4v sg0, sg1, sg2, sg3;       // staging registers
    #define ISSUE(gid)  { const uint4v* g_ = (const uint4v*)(wt + (gid) * 32768); \
                          sg0 = g_[tid]; sg1 = g_[tid + 512]; sg2 = g_[tid + 1024]; sg3 = g_[tid + 1536]; }
    #define COMMIT(gid) { uint4v* d_ = (uint4v*)(s_w + ((gid) & 1) * 32768); \
                          d_[tid] = sg0; d_[tid + 512] = sg1; d_[tid + 1024] = sg2; d_[tid + 1536] = sg3; }

    ISSUE(0)
    if (tid < 6) s_od[tid] = ray[r * 6 + tid];
    __syncthreads();
    const float d0 = s_od[3], d1 = s_od[4], d2 = s_od[5];

    // ---- posenc(x,10) via 1 sinf/cosf + 9 doublings per coord; col 63 = 0 ---
    {
        const int grp = tid >> 7, p = tid & 127;
        const int sw = (p & 7) << 4;
        unsigned char* wp0 = s_act + p * 512;
        if (grp < 3) {
            float tv = t[r * 129 + 1 + p];
            float x = s_od[grp] + tv * s_od[grp + 3];
            *(unsigned short*)(wp0 + ((2 * grp) ^ sw)) = f2bf(x);
            float sv = sinf(x), cv = cosf(x);
            #pragma unroll
            for (int l = 0; l < 10; ++l) {
                *(unsigned short*)(wp0 + ((2 * (3 + 6 * l + grp)) ^ sw)) = f2bf(sv);
                *(unsigned short*)(wp0 + ((2 * (6 + 6 * l + grp)) ^ sw)) = f2bf(cv);
                float ns = 2.f * sv * cv;
                float nc = 1.f - 2.f * sv * sv;
                sv = ns; cv = nc;
            }
        } else {
            *(unsigned short*)(wp0 + (126 ^ sw)) = 0;
        }
    }
    // de = posenc(d,4): 27 per-ray features
    if (tid < 27) {
        int f = tid; float v;
        if (f < 3) v = (f == 0) ? d0 : ((f == 1) ? d1 : d2);
        else {
            int q = f - 3, l = q / 6, rm = q % 6, c = rm % 3;
            float dc = (c == 0) ? d0 : ((c == 1) ? d1 : d2);
            float a = dc * (float)(1 << l);
            v = (rm < 3) ? sinf(a) : cosf(a);
        }
        s_de[f] = v;
    }
    if (tid < 256) s_ws[tid]  = Wsg[tid];
    if (tid < 384) s_wc2[tid] = Wc2g[tid];
    __syncthreads();

    // ---- P(0): commit W0t, issue c1; L0 B-frags; b0; decont --------------
    COMMIT(0)
    ISSUE(1)
    short8 B0[4];
    #pragma unroll
    for (int ks = 0; ks < 4; ++ks)
        B0[ks] = *(const short8*)(wp + ((32 * ks + 16 * hi) ^ swz));
    if (tid < 256) s_bias[tid] = b0g[tid];
    if (tid < 128) {
        float acc = bc1g[tid];
        for (int k = 0; k < 27; ++k)
            acc = fmaf(s_de[k], Wc1g[(256 + k) * 128 + tid], acc);
        s_decont[tid] = acc;
    }
    __syncthreads();

    // ---- P(1): layer 0 (K=64, row stride 128B), 4 n-tiles per wave --------
    COMMIT(1)
    ISSUE(2)
    #pragma unroll
    for (int nt = 0; nt < 4; ++nt) {
        const int ntg = cgrp * 4 + nt;
        const int nb = ntg * 32;
        const unsigned char* ap = s_w + (ntg * 32 + ls) * 128;
        f32x16 acc;
        #pragma unroll
        for (int g = 0; g < 4; ++g) {
            f32x4 bv = *(const f32x4*)&s_bias[nb + 4 * hi + 8 * g];
            acc[4*g+0] = bv[0]; acc[4*g+1] = bv[1]; acc[4*g+2] = bv[2]; acc[4*g+3] = bv[3];
        }
        #pragma unroll
        for (int ks = 0; ks < 4; ++ks) {
            short8 A = *(const short8*)(ap + ((32 * ks + 16 * hi) ^ swz));
            acc = MFMA32(A, B0[ks], acc);
        }
        #pragma unroll
        for (int g = 0; g < 4; ++g) {
            int n = nb + 4 * hi + 8 * g;
            unsigned long long pk =
                  (unsigned long long)f2bf(fmaxf(acc[4*g+0], 0.f))
                | ((unsigned long long)f2bf(fmaxf(acc[4*g+1], 0.f)) << 16)
                | ((unsigned long long)f2bf(fmaxf(acc[4*g+2], 0.f)) << 32)
                | ((unsigned long long)f2bf(fmaxf(acc[4*g+3], 0.f)) << 48);
            *(unsigned long long*)(wp + ((2 * n) ^ swz)) = pk;
        }
    }
    __syncthreads();

    short8 Bf[16];

    // ==================== Layer 1: chunks gid 1..4 =========================
    #pragma unroll
    for (int ks = 0; ks < 16; ++ks)
        Bf[ks] = *(const short8*)(wp + ((32 * ks + 16 * hi) ^ swz));
    if (tid < 256) s_bias[tid] = b1g[tid];
    __syncthreads();
    for (int c = 0; c < 4; ++c) {
        const int gid = 1 + c;
        COMMIT(gid + 1)
        ISSUE(gid + 2)
        mfma_chunk_k256(s_w + (gid & 1) * 32768 + (cgrp * 32 + ls) * 512,
                        Bf, s_bias, c * 64 + cgrp * 32, hi, swz, wp);
        __syncthreads();
    }

    // ==================== Layer 2: chunks gid 5..8 =========================
    #pragma unroll
    for (int ks = 0; ks < 16; ++ks)
        Bf[ks] = *(const short8*)(wp + ((32 * ks + 16 * hi) ^ swz));
    if (tid < 256) s_bias[tid] = b2g[tid];
    __syncthreads();
    for (int c = 0; c < 4; ++c) {
        const int gid = 5 + c;
        if (gid + 1 <= 10) COMMIT(gid + 1)
        if (gid + 2 <= 10) ISSUE(gid + 2)
        mfma_chunk_k256(s_w + (gid & 1) * 32768 + (cgrp * 32 + ls) * 512,
                        Bf, s_bias, c * 64 + cgrp * 32, hi, swz, wp);
        __syncthreads();
    }

    // ============ sigma head (reads h3) + Wc1 B-frags ======================
    {
        const int p = tid >> 2, q = tid & 3;
        const int pswz = (p & 7) << 4;
        float sum = 0.f;
        #pragma unroll
        for (int g = 0; g < 8; ++g) {
            short8 h = *(const short8*)(s_act + p * 512 + ((q * 128 + g * 16) ^ pswz));
            int kb = q * 64 + g * 8;
            #pragma unroll
            for (int j = 0; j < 8; ++j)
                sum = fmaf(bf2f((unsigned short)h[j]), s_ws[kb + j], sum);
        }
        sum += __shfl_xor(sum, 1);
        sum += __shfl_xor(sum, 2);
        if (q == 0) {
            float x = sum + bsg[0];
            s_sigma[p] = fmaxf(x, 0.f) + log1pf(expf(-fabsf(x)));
        }
    }
    #pragma unroll
    for (int ks = 0; ks < 16; ++ks)
        Bf[ks] = *(const short8*)(wp + ((32 * ks + 16 * hi) ^ swz));
    __syncthreads();

    // ==================== Wc1: chunks gid 9..10 (N=128) ====================
    for (int c = 0; c < 2; ++c) {
        const int gid = 9 + c;
        if (gid + 1 <= 10) COMMIT(gid + 1)
        mfma_chunk_k256(s_w + (gid & 1) * 32768 + (cgrp * 32 + ls) * 512,
                        Bf, s_decont, c * 64 + cgrp * 32, hi, swz, wp);
        __syncthreads();
    }

    // ================= color head: sigmoid(hc @ Wc2 + bc2) =================
    {
        const int p = tid >> 2, q = tid & 3;
        const int pswz = (p & 7) << 4;
        float c0 = 0.f, c1 = 0.f, c2 = 0.f;
        #pragma unroll
        for (int g = 0; g < 4; ++g) {
            short8 h = *(const short8*)(s_act + p * 512 + ((q * 64 + g * 16) ^ pswz));
            int kb = q * 32 + g * 8;
            #pragma unroll
            for (int j = 0; j < 8; ++j) {
                float hv = bf2f((unsigned short)h[j]);
                c0 = fmaf(hv, s_wc2[(kb + j) * 3 + 0], c0);
                c1 = fmaf(hv, s_wc2[(kb + j) * 3 + 1], c1);
                c2 = fmaf(hv, s_wc2[(kb + j) * 3 + 2], c2);
            }
        }
        c0 += __shfl_xor(c0, 1); c0 += __shfl_xor(c0, 2);
        c1 += __shfl_xor(c1, 1); c1 += __shfl_xor(c1, 2);
        c2 += __shfl_xor(c2, 1); c2 += __shfl_xor(c2, 2);
        if (q == 0) {
            s_color[p * 3 + 0] = 1.f / (1.f + expf(-(c0 + bc2g[0])));
            s_color[p * 3 + 1] = 1.f / (1.f + expf(-(c1 + bc2g[1])));
            s_color[p * 3 + 2] = 1.f / (1.f + expf(-(c2 + bc2g[2])));
        }
    }
    __syncthreads();

    // ======================= render (sort/scan/composite) ==================
    if (tid < 129) s_t[tid] = t[r * 129 + tid];
    __syncthreads();
    if (tid < 129) {
        float v = s_t[tid];
        int rank = 0;
        for (int j = 0; j < 129; ++j) {
            float u = s_t[j];
            rank += (u < v) || (u == v && j < tid);
        }
        s_ts[rank] = v;
    }
    __syncthreads();
    if (tid < 128) {
        float dt = s_ts[tid + 1] - s_ts[tid];
        float sd = s_sigma[tid] * dt;
        s_sdt[tid] = sd;
        s_cum[tid] = sd;
    }
    __syncthreads();
    for (int off = 1; off < 128; off <<= 1) {
        float add = (tid < 128 && tid >= off) ? s_cum[tid - off] : 0.f;
        __syncthreads();
        if (tid < 128) s_cum[tid] += add;
        __syncthreads();
    }
    if (tid < 128) {
        float Ti = (tid == 0) ? 1.f : expf(-s_cum[tid - 1]);
        float alpha = 1.f - expf(-s_sdt[tid]);
        float w = Ti * alpha;
        s_wi[tid] = w;
        wi_out[r * 128 + tid] = w;
    }
    __syncthreads();
    if (tid < 3) {
        float acc = 0.f;
        for (int i = 0; i < 128; ++i)
            acc = fmaf(s_wi[i], s_color[i * 3 + tid], acc);
        rgb_out[r * 3 + tid] = acc;
    }
    #undef ISSUE
    #undef COMMIT
}

extern "C" void kernel_launch(void* const* d_in, const int* in_sizes, int n_in,
                              void* d_out, int out_size, void* d_ws, size_t ws_size,
                              hipStream_t stream)
{
    const float* ray = (const float*)d_in[0];
    const float* t   = (const float*)d_in[1];
    const float* W0  = (const float*)d_in[2];
    const float* b0  = (const float*)d_in[3];
    const float* W1  = (const float*)d_in[4];
    const float* b1  = (const float*)d_in[5];
    const float* W2  = (const float*)d_in[6];
    const float* b2  = (const float*)d_in[7];
    const float* Ws  = (const float*)d_in[8];
    const float* bs  = (const float*)d_in[9];
    const float* Wc1 = (const float*)d_in[10];
    const float* bc1 = (const float*)d_in[11];
    const float* Wc2 = (const float*)d_in[12];
    const float* bc2 = (const float*)d_in[13];

    unsigned short* wt = (unsigned short*)d_ws;   // 11 x 32KB weight chunks
    float* rgb_out = (float*)d_out;               // R*3
    float* wi_out  = rgb_out + R_ * 3;            // R*128

    hipLaunchKernelGGL(prep_weights, dim3(704), dim3(256), 0, stream,
                       W0, W1, W2, Wc1, wt);
    hipLaunchKernelGGL(nerf_kernel, dim3(R_), dim3(512), 0, stream,
                       ray, t, b0, b1, b2, Ws, bs, Wc1, bc1, Wc2, bc2,
                       (const unsigned char*)wt, rgb_out, wi_out);
}